// Round 3
// baseline (602.277 us; speedup 1.0000x reference)
//
#include <hip/hip_runtime.h>
#include <math.h>

typedef float f2 __attribute__((ext_vector_type(2)));
typedef float f4 __attribute__((ext_vector_type(4)));

// Problem constants (fixed by setup_inputs)
#define BATCH 32768
#define SS 16
#define DI 14
#define BQ 256
#define NC 7
#define RPL 4                                   // rows per lane
#define THREADS 256
#define BLOCKS (BATCH * SS / (THREADS * RPL))   // 512

// fp32 top-2 gap below which we redo the row's argmax in fp64 (~2e-4 of rows).
#define MARGIN 3.0e-4f

// ws layout
#define WS_KP64_OFF 0                         // double2[256*7]  (28672 B) k fp64, pattern-major
#define WS_KF32_OFF 28672                     // float [256*16]  (16384 B) k fp32, padded to 16
#define WS_TF_OFF   (28672 + 16384)           // float [256*7]   ( 7168 B) per-pattern class table
#define WS_ZB_OFF   (28672 + 16384 + 7168)    // float [7]       head bias: bm*sum(Wb)+bb

__global__ __launch_bounds__(256) void precompute_kernel(
    const float* __restrict__ lookup,
    const float* __restrict__ g_st, const float* __restrict__ b_st,
    const float* __restrict__ g_pp, const float* __restrict__ b_pp,
    const float* __restrict__ Wv,  const float* __restrict__ Wo,
    const float* __restrict__ Wm,  const float* __restrict__ bm,
    const float* __restrict__ Wb,  const float* __restrict__ bb,
    double2* __restrict__ kp64, float* __restrict__ kf32,
    float* __restrict__ Tf, float* __restrict__ zbf)
{
    __shared__ double G1s[256][7];   // (Wo.T @ Wm.T)  : [p][c]
    __shared__ double Gs[14][7];     // Wv.T @ G1      : [d][c]
    const int tid = threadIdx.x;

    // G1[p][c] = sum_o Wo[o,p] * Wm[c,o]
    {
        const int p = tid;
        for (int c = 0; c < NC; ++c) {
            double acc = 0.0;
            for (int o = 0; o < 28; ++o)
                acc += (double)Wo[o * 256 + p] * (double)Wm[c * 28 + o];
            G1s[p][c] = acc;
        }
    }
    __syncthreads();
    // G[d][c] = sum_p Wv[p,d] * G1[p][c]
    if (tid < DI * NC) {
        const int d = tid / NC, c = tid % NC;
        double acc = 0.0;
        for (int p = 0; p < 256; ++p)
            acc += (double)Wv[p * DI + d] * G1s[p][c];
        Gs[d][c] = acc;
    }
    __syncthreads();

    // Per stored pattern j: LayerNorm in fp64, emit k (f64 + f32) and T row.
    {
        const int j = tid;
        double xr[DI];
        double sum = 0.0;
        for (int d = 0; d < DI; ++d) { xr[d] = (double)lookup[j * DI + d]; sum += xr[d]; }
        const double mu = sum * (1.0 / (double)DI);
        double vs = 0.0;
        for (int d = 0; d < DI; ++d) { const double t = xr[d] - mu; vs += t * t; }
        const double rs = 1.0 / sqrt(vs * (1.0 / (double)DI) + 1e-5);

        double kj[DI], vl[DI];
        for (int d = 0; d < DI; ++d) {
            const double nrm = (xr[d] - mu) * rs;
            kj[d] = nrm * (double)g_st[d] + (double)b_st[d];
            vl[d] = nrm * (double)g_pp[d] + (double)b_pp[d];
        }
        for (int d2 = 0; d2 < DI / 2; ++d2) {
            double2 kv; kv.x = kj[2 * d2]; kv.y = kj[2 * d2 + 1];
            kp64[j * 7 + d2] = kv;
        }
        for (int d = 0; d < DI; ++d) kf32[j * 16 + d] = (float)kj[d];
        kf32[j * 16 + 14] = 0.0f;
        kf32[j * 16 + 15] = 0.0f;
        for (int c = 0; c < NC; ++c) {
            double acc = 0.0;
            for (int d = 0; d < DI; ++d) acc += vl[d] * Gs[d][c];
            Tf[j * NC + c] = (float)acc;
        }
    }
    if (tid < NC) {
        double wbsum = 0.0;
        for (int s = 0; s < SS; ++s) wbsum += (double)Wb[s];
        zbf[tid] = (float)((double)bm[tid] * wbsum + (double)bb[0]);
    }
}

__global__ __launch_bounds__(THREADS) void hopfield_kernel(
    const float* __restrict__ x,
    const float* __restrict__ g_sp, const float* __restrict__ b_sp,
    const float* __restrict__ kf32, const float* __restrict__ Tf,
    const double2* __restrict__ kp64, const float* __restrict__ zbf,
    const float* __restrict__ Wb,
    float* __restrict__ out)
{
    const int tid = threadIdx.x;
    const long G    = (long)blockIdx.x * THREADS + tid;   // global lane id
    const long row0 = G * RPL;                            // first of 4 owned rows

    // ---- Load 4 rows (56 floats, 16B-aligned since row0*DI*4 = 224*G) ----
    const f4* __restrict__ xp = (const f4*)(x + row0 * DI);
    f4 xv[14];
    #pragma unroll
    for (int t = 0; t < 14; ++t) xv[t] = xp[t];

    // ---- fp32 LayerNorm per row -> q2[r][t] = (q[2t], q[2t+1]) ----
    f2 q2[RPL][7];
    #pragma unroll
    for (int r = 0; r < RPL; ++r) {
        float s = 0.f;
        #pragma unroll
        for (int d = 0; d < DI; ++d) {
            const int idx = r * DI + d;
            s += xv[idx >> 2][idx & 3];
        }
        const float mu = s * (1.0f / DI);
        float v = 0.f;
        #pragma unroll
        for (int d = 0; d < DI; ++d) {
            const int idx = r * DI + d;
            const float t = xv[idx >> 2][idx & 3] - mu;
            v += t * t;
        }
        const float rs = rsqrtf(v * (1.0f / DI) + 1e-5f);
        #pragma unroll
        for (int t = 0; t < 7; ++t) {
            const int i0 = r * DI + 2 * t, i1 = i0 + 1;
            f2 qq;
            qq.x = (xv[i0 >> 2][i0 & 3] - mu) * rs * g_sp[2 * t]     + b_sp[2 * t];
            qq.y = (xv[i1 >> 2][i1 & 3] - mu) * rs * g_sp[2 * t + 1] + b_sp[2 * t + 1];
            q2[r][t] = qq;
        }
    }

    // ---- Argmax over 256 patterns; k via wave-uniform loads (SGPR path) ----
    float best[RPL], sec[RPL];
    int bj[RPL];
    #pragma unroll
    for (int r = 0; r < RPL; ++r) { best[r] = -3e38f; sec[r] = -3e38f; bj[r] = 0; }

    const f4* __restrict__ kp = (const f4*)kf32;
    #pragma unroll 4
    for (int j = 0; j < BQ; ++j) {
        const f4 ka = kp[4 * j + 0];
        const f4 kb = kp[4 * j + 1];
        const f4 kc = kp[4 * j + 2];
        const f4 kd = kp[4 * j + 3];
        f2 kk[7];
        kk[0].x = ka.x; kk[0].y = ka.y;
        kk[1].x = ka.z; kk[1].y = ka.w;
        kk[2].x = kb.x; kk[2].y = kb.y;
        kk[3].x = kb.z; kk[3].y = kb.w;
        kk[4].x = kc.x; kk[4].y = kc.y;
        kk[5].x = kc.z; kk[5].y = kc.w;
        kk[6].x = kd.x; kk[6].y = kd.y;

        #pragma unroll
        for (int r = 0; r < RPL; ++r) {
            f2 acc; acc.x = 0.f; acc.y = 0.f;
            #pragma unroll
            for (int t = 0; t < 7; ++t)
                acc = __builtin_elementwise_fma(q2[r][t], kk[t], acc);
            const float a = acc.x + acc.y;
            const bool cgt = a > best[r];
            sec[r]  = __builtin_amdgcn_fmed3f(a, best[r], sec[r]); // new 2nd-best
            best[r] = fmaxf(best[r], a);
            bj[r]   = cgt ? j : bj[r];
        }
    }

    // ---- Rare fp64 refine for rows whose fp32 top-2 gap is inside MARGIN ----
    #pragma unroll 1
    for (int r = 0; r < RPL; ++r) {
        if (best[r] - sec[r] < MARGIN) {
            const float* xr = x + (row0 + r) * DI;
            double xd[DI]; double s = 0.0;
            #pragma unroll 1
            for (int d = 0; d < DI; ++d) { xd[d] = (double)xr[d]; s += xd[d]; }
            const double mu = s * (1.0 / (double)DI);
            double v = 0.0;
            #pragma unroll 1
            for (int d = 0; d < DI; ++d) { const double t = xd[d] - mu; v += t * t; }
            const double rsd = 1.0 / sqrt(v * (1.0 / (double)DI) + 1e-5);
            double q[DI];
            #pragma unroll 1
            for (int d = 0; d < DI; ++d)
                q[d] = (xd[d] - mu) * rsd * (double)g_sp[d] + (double)b_sp[d];
            double bv = -1e300; int bi = 0;
            #pragma unroll 1
            for (int j = 0; j < BQ; ++j) {
                double a = 0.0;
                #pragma unroll 1
                for (int d2 = 0; d2 < 7; ++d2) {
                    const double2 kv = kp64[j * 7 + d2];
                    a += q[2 * d2] * kv.x + q[2 * d2 + 1] * kv.y;
                }
                if (a > bv) { bv = a; bi = j; }
            }
            bj[r] = bi;
        }
    }

    // ---- Head: z[c] = zb[c] + sum_s Wb[s]*T[jstar(s),c]; softmax over 7. ----
    // Lane owns s = s0..s0+3 of batch G/4; reduce across the 4 lanes of a batch.
    const int s0 = (int)(G & 3) * RPL;
    float pz[NC];
    #pragma unroll
    for (int c = 0; c < NC; ++c) pz[c] = 0.f;
    #pragma unroll
    for (int r = 0; r < RPL; ++r) {
        const float wb = Wb[s0 + r];
        const float* tr = Tf + bj[r] * NC;
        #pragma unroll
        for (int c = 0; c < NC; ++c) pz[c] = fmaf(wb, tr[c], pz[c]);
    }
    #pragma unroll
    for (int m = 1; m < 4; m <<= 1) {
        #pragma unroll
        for (int c = 0; c < NC; ++c) pz[c] += __shfl_xor(pz[c], m);
    }
    if ((G & 3) == 0) {
        const long batch = G >> 2;
        float z[NC];
        float mx = -3e38f;
        #pragma unroll
        for (int c = 0; c < NC; ++c) { z[c] = pz[c] + zbf[c]; mx = fmaxf(mx, z[c]); }
        float den = 0.f;
        float e[NC];
        #pragma unroll
        for (int c = 0; c < NC; ++c) { e[c] = __expf(z[c] - mx); den += e[c]; }
        const float inv = 1.0f / den;
        #pragma unroll
        for (int c = 0; c < NC; ++c) out[batch * NC + c] = e[c] * inv;
    }
}

extern "C" void kernel_launch(void* const* d_in, const int* in_sizes, int n_in,
                              void* d_out, int out_size, void* d_ws, size_t ws_size,
                              hipStream_t stream) {
    const float* x      = (const float*)d_in[0];
    const float* lookup = (const float*)d_in[1];
    const float* g_st   = (const float*)d_in[2];
    const float* b_st   = (const float*)d_in[3];
    const float* g_sp   = (const float*)d_in[4];
    const float* b_sp   = (const float*)d_in[5];
    const float* g_pp   = (const float*)d_in[6];
    const float* b_pp   = (const float*)d_in[7];
    const float* Wv     = (const float*)d_in[8];
    const float* Wo     = (const float*)d_in[9];
    const float* Wm     = (const float*)d_in[10];
    const float* bm     = (const float*)d_in[11];
    const float* Wb     = (const float*)d_in[12];
    const float* bb     = (const float*)d_in[13];

    double2* kp64 = (double2*)((char*)d_ws + WS_KP64_OFF);
    float*   kf32 = (float*)((char*)d_ws + WS_KF32_OFF);
    float*   Tf   = (float*)((char*)d_ws + WS_TF_OFF);
    float*   zbf  = (float*)((char*)d_ws + WS_ZB_OFF);

    precompute_kernel<<<1, 256, 0, stream>>>(lookup, g_st, b_st, g_pp, b_pp,
                                             Wv, Wo, Wm, bm, Wb, bb,
                                             kp64, kf32, Tf, zbf);
    hopfield_kernel<<<BLOCKS, THREADS, 0, stream>>>(x, g_sp, b_sp, kf32, Tf,
                                                    kp64, zbf, Wb, (float*)d_out);
}

// Round 4
// 441.188 us; speedup vs baseline: 1.3651x; 1.3651x over previous
//
#include <hip/hip_runtime.h>
#include <math.h>

typedef float f2 __attribute__((ext_vector_type(2)));
typedef float f4 __attribute__((ext_vector_type(4)));

// Problem constants (fixed by setup_inputs)
#define BATCH 32768
#define SS 16
#define DI 14
#define BQ 256
#define NC 7
#define RPL 2                                   // rows per lane
#define THREADS 256
#define BLOCKS (BATCH * SS / (THREADS * RPL))   // 1024

// fp32 top-2 gap below which we redo the row's argmax in fp64 (~3e-4 of rows).
#define MARGIN 3.0e-4f

// ws layout
#define WS_KP64_OFF 0                         // double2[256*7]  (28672 B) k fp64, pattern-major
#define WS_KF32_OFF 28672                     // float [256*16]  (16384 B) k fp32, padded to 16
#define WS_TF_OFF   (28672 + 16384)           // float [256*7]   ( 7168 B) per-pattern class table
#define WS_ZB_OFF   (28672 + 16384 + 7168)    // float [7]       head bias: bm*sum(Wb)+bb

__global__ __launch_bounds__(256) void precompute_kernel(
    const float* __restrict__ lookup,
    const float* __restrict__ g_st, const float* __restrict__ b_st,
    const float* __restrict__ g_pp, const float* __restrict__ b_pp,
    const float* __restrict__ Wv,  const float* __restrict__ Wo,
    const float* __restrict__ Wm,  const float* __restrict__ bm,
    const float* __restrict__ Wb,  const float* __restrict__ bb,
    double2* __restrict__ kp64, float* __restrict__ kf32,
    float* __restrict__ Tf, float* __restrict__ zbf)
{
    __shared__ double G1s[256][7];   // (Wo.T @ Wm.T)  : [p][c]
    __shared__ double Gs[14][7];     // Wv.T @ G1      : [d][c]
    const int tid = threadIdx.x;

    {
        const int p = tid;
        for (int c = 0; c < NC; ++c) {
            double acc = 0.0;
            for (int o = 0; o < 28; ++o)
                acc += (double)Wo[o * 256 + p] * (double)Wm[c * 28 + o];
            G1s[p][c] = acc;
        }
    }
    __syncthreads();
    if (tid < DI * NC) {
        const int d = tid / NC, c = tid % NC;
        double acc = 0.0;
        for (int p = 0; p < 256; ++p)
            acc += (double)Wv[p * DI + d] * G1s[p][c];
        Gs[d][c] = acc;
    }
    __syncthreads();

    {
        const int j = tid;
        double xr[DI];
        double sum = 0.0;
        for (int d = 0; d < DI; ++d) { xr[d] = (double)lookup[j * DI + d]; sum += xr[d]; }
        const double mu = sum * (1.0 / (double)DI);
        double vs = 0.0;
        for (int d = 0; d < DI; ++d) { const double t = xr[d] - mu; vs += t * t; }
        const double rs = 1.0 / sqrt(vs * (1.0 / (double)DI) + 1e-5);

        double kj[DI], vl[DI];
        for (int d = 0; d < DI; ++d) {
            const double nrm = (xr[d] - mu) * rs;
            kj[d] = nrm * (double)g_st[d] + (double)b_st[d];
            vl[d] = nrm * (double)g_pp[d] + (double)b_pp[d];
        }
        for (int d2 = 0; d2 < DI / 2; ++d2) {
            double2 kv; kv.x = kj[2 * d2]; kv.y = kj[2 * d2 + 1];
            kp64[j * 7 + d2] = kv;
        }
        for (int d = 0; d < DI; ++d) kf32[j * 16 + d] = (float)kj[d];
        kf32[j * 16 + 14] = 0.0f;
        kf32[j * 16 + 15] = 0.0f;
        for (int c = 0; c < NC; ++c) {
            double acc = 0.0;
            for (int d = 0; d < DI; ++d) acc += vl[d] * Gs[d][c];
            Tf[j * NC + c] = (float)acc;
        }
    }
    if (tid < NC) {
        double wbsum = 0.0;
        for (int s = 0; s < SS; ++s) wbsum += (double)Wb[s];
        zbf[tid] = (float)((double)bm[tid] * wbsum + (double)bb[0]);
    }
}

// Cold path: exact fp64 argmax for one row. __noinline__ keeps its arrays /
// scratch out of the hot kernel's register allocation.
__device__ __noinline__ int refine_row(const float* __restrict__ xrow,
                                       const double2* __restrict__ kp64,
                                       const float* __restrict__ g_sp,
                                       const float* __restrict__ b_sp)
{
    double xv[DI]; double sum = 0.0;
    for (int d = 0; d < DI; ++d) { xv[d] = (double)xrow[d]; sum += xv[d]; }
    const double mu = sum * (1.0 / (double)DI);
    double vs = 0.0;
    for (int d = 0; d < DI; ++d) { const double t = xv[d] - mu; vs += t * t; }
    const double rs = 1.0 / sqrt(vs * (1.0 / (double)DI) + 1e-5);
    double q[DI];
    for (int d = 0; d < DI; ++d)
        q[d] = (xv[d] - mu) * rs * (double)g_sp[d] + (double)b_sp[d];

    double best = -1e300; int bj = 0;
    for (int j = 0; j < BQ; ++j) {
        double a = 0.0;
        for (int d2 = 0; d2 < 7; ++d2) {
            const double2 kv = kp64[j * 7 + d2];
            a += q[2 * d2] * kv.x + q[2 * d2 + 1] * kv.y;
        }
        if (a > best) { best = a; bj = j; }
    }
    return bj;
}

__global__ __launch_bounds__(THREADS, 4) void hopfield_kernel(
    const float* __restrict__ x,
    const float* __restrict__ g_sp, const float* __restrict__ b_sp,
    const float* __restrict__ kf32, const float* __restrict__ Tf,
    const double2* __restrict__ kp64, const float* __restrict__ zbf,
    const float* __restrict__ Wb,
    float* __restrict__ out)
{
    const int tid = threadIdx.x;
    const long G    = (long)blockIdx.x * THREADS + tid;   // global lane id
    const long row0 = G * RPL;                            // first of 2 owned rows

    // ---- Load 2 rows = 28 floats = 7 f4 (112 B per lane, 16B-aligned) ----
    const f4* __restrict__ xp = (const f4*)(x + row0 * DI);
    const f4 xa = xp[0], xb = xp[1], xc = xp[2], xd = xp[3],
             xe = xp[4], xf = xp[5], xg = xp[6];

    // gamma/beta (wave-uniform -> SGPRs)
    const float g0 = g_sp[0], g1 = g_sp[1], g2 = g_sp[2],  g3 = g_sp[3],
                g4 = g_sp[4], g5 = g_sp[5], g6 = g_sp[6],  g7 = g_sp[7],
                g8 = g_sp[8], g9 = g_sp[9], g10 = g_sp[10], g11 = g_sp[11],
                g12 = g_sp[12], g13 = g_sp[13];
    const float h0 = b_sp[0], h1 = b_sp[1], h2 = b_sp[2],  h3 = b_sp[3],
                h4 = b_sp[4], h5 = b_sp[5], h6 = b_sp[6],  h7 = b_sp[7],
                h8 = b_sp[8], h9 = b_sp[9], h10 = b_sp[10], h11 = b_sp[11],
                h12 = b_sp[12], h13 = b_sp[13];

    // ---- fp32 LayerNorm, row 0 (elements xa.x .. xd.y) ----
    f2 qa0, qb0, qc0, qd0, qe0, qf0, qg0;
    {
        const float s = xa.x + xa.y + xa.z + xa.w + xb.x + xb.y + xb.z + xb.w
                      + xc.x + xc.y + xc.z + xc.w + xd.x + xd.y;
        const float mu = s * (1.0f / DI);
        float v = 0.f, t;
        t = xa.x - mu; v = fmaf(t, t, v);  t = xa.y - mu; v = fmaf(t, t, v);
        t = xa.z - mu; v = fmaf(t, t, v);  t = xa.w - mu; v = fmaf(t, t, v);
        t = xb.x - mu; v = fmaf(t, t, v);  t = xb.y - mu; v = fmaf(t, t, v);
        t = xb.z - mu; v = fmaf(t, t, v);  t = xb.w - mu; v = fmaf(t, t, v);
        t = xc.x - mu; v = fmaf(t, t, v);  t = xc.y - mu; v = fmaf(t, t, v);
        t = xc.z - mu; v = fmaf(t, t, v);  t = xc.w - mu; v = fmaf(t, t, v);
        t = xd.x - mu; v = fmaf(t, t, v);  t = xd.y - mu; v = fmaf(t, t, v);
        const float rs = rsqrtf(v * (1.0f / DI) + 1e-5f);
        qa0.x = (xa.x - mu) * rs * g0  + h0;   qa0.y = (xa.y - mu) * rs * g1  + h1;
        qb0.x = (xa.z - mu) * rs * g2  + h2;   qb0.y = (xa.w - mu) * rs * g3  + h3;
        qc0.x = (xb.x - mu) * rs * g4  + h4;   qc0.y = (xb.y - mu) * rs * g5  + h5;
        qd0.x = (xb.z - mu) * rs * g6  + h6;   qd0.y = (xb.w - mu) * rs * g7  + h7;
        qe0.x = (xc.x - mu) * rs * g8  + h8;   qe0.y = (xc.y - mu) * rs * g9  + h9;
        qf0.x = (xc.z - mu) * rs * g10 + h10;  qf0.y = (xc.w - mu) * rs * g11 + h11;
        qg0.x = (xd.x - mu) * rs * g12 + h12;  qg0.y = (xd.y - mu) * rs * g13 + h13;
    }
    // ---- fp32 LayerNorm, row 1 (elements xd.z .. xg.w) ----
    f2 qa1, qb1, qc1, qd1, qe1, qf1, qg1;
    {
        const float s = xd.z + xd.w + xe.x + xe.y + xe.z + xe.w + xf.x + xf.y
                      + xf.z + xf.w + xg.x + xg.y + xg.z + xg.w;
        const float mu = s * (1.0f / DI);
        float v = 0.f, t;
        t = xd.z - mu; v = fmaf(t, t, v);  t = xd.w - mu; v = fmaf(t, t, v);
        t = xe.x - mu; v = fmaf(t, t, v);  t = xe.y - mu; v = fmaf(t, t, v);
        t = xe.z - mu; v = fmaf(t, t, v);  t = xe.w - mu; v = fmaf(t, t, v);
        t = xf.x - mu; v = fmaf(t, t, v);  t = xf.y - mu; v = fmaf(t, t, v);
        t = xf.z - mu; v = fmaf(t, t, v);  t = xf.w - mu; v = fmaf(t, t, v);
        t = xg.x - mu; v = fmaf(t, t, v);  t = xg.y - mu; v = fmaf(t, t, v);
        t = xg.z - mu; v = fmaf(t, t, v);  t = xg.w - mu; v = fmaf(t, t, v);
        const float rs = rsqrtf(v * (1.0f / DI) + 1e-5f);
        qa1.x = (xd.z - mu) * rs * g0  + h0;   qa1.y = (xd.w - mu) * rs * g1  + h1;
        qb1.x = (xe.x - mu) * rs * g2  + h2;   qb1.y = (xe.y - mu) * rs * g3  + h3;
        qc1.x = (xe.z - mu) * rs * g4  + h4;   qc1.y = (xe.w - mu) * rs * g5  + h5;
        qd1.x = (xf.x - mu) * rs * g6  + h6;   qd1.y = (xf.y - mu) * rs * g7  + h7;
        qe1.x = (xf.z - mu) * rs * g8  + h8;   qe1.y = (xf.w - mu) * rs * g9  + h9;
        qf1.x = (xg.x - mu) * rs * g10 + h10;  qf1.y = (xg.y - mu) * rs * g11 + h11;
        qg1.x = (xg.z - mu) * rs * g12 + h12;  qg1.y = (xg.w - mu) * rs * g13 + h13;
    }

    // ---- Argmax over 256 patterns; k via loop-uniform loads (L1-resident) ----
    float best0 = -3e38f, sec0 = -3e38f, best1 = -3e38f, sec1 = -3e38f;
    int bj0 = 0, bj1 = 0;
    const f4* __restrict__ kp = (const f4*)kf32;
    #pragma unroll 4
    for (int j = 0; j < BQ; ++j) {
        const f4 ka = kp[4 * j + 0];
        const f4 kb = kp[4 * j + 1];
        const f4 kc = kp[4 * j + 2];
        const f4 kd = kp[4 * j + 3];
        f2 k0, k1, k2, k3, k4, k5, k6;
        k0.x = ka.x; k0.y = ka.y;  k1.x = ka.z; k1.y = ka.w;
        k2.x = kb.x; k2.y = kb.y;  k3.x = kb.z; k3.y = kb.w;
        k4.x = kc.x; k4.y = kc.y;  k5.x = kc.z; k5.y = kc.w;
        k6.x = kd.x; k6.y = kd.y;

        f2 acc0 = qa0 * k0;
        acc0 = __builtin_elementwise_fma(qb0, k1, acc0);
        acc0 = __builtin_elementwise_fma(qc0, k2, acc0);
        acc0 = __builtin_elementwise_fma(qd0, k3, acc0);
        acc0 = __builtin_elementwise_fma(qe0, k4, acc0);
        acc0 = __builtin_elementwise_fma(qf0, k5, acc0);
        acc0 = __builtin_elementwise_fma(qg0, k6, acc0);
        const float a0 = acc0.x + acc0.y;

        f2 acc1 = qa1 * k0;
        acc1 = __builtin_elementwise_fma(qb1, k1, acc1);
        acc1 = __builtin_elementwise_fma(qc1, k2, acc1);
        acc1 = __builtin_elementwise_fma(qd1, k3, acc1);
        acc1 = __builtin_elementwise_fma(qe1, k4, acc1);
        acc1 = __builtin_elementwise_fma(qf1, k5, acc1);
        acc1 = __builtin_elementwise_fma(qg1, k6, acc1);
        const float a1 = acc1.x + acc1.y;

        const bool c0 = a0 > best0;
        sec0  = __builtin_amdgcn_fmed3f(a0, best0, sec0);
        best0 = fmaxf(best0, a0);
        bj0   = c0 ? j : bj0;

        const bool c1 = a1 > best1;
        sec1  = __builtin_amdgcn_fmed3f(a1, best1, sec1);
        best1 = fmaxf(best1, a1);
        bj1   = c1 ? j : bj1;
    }

    // ---- Rare fp64 refine when fp32 top-2 gap is inside the error margin ----
    if (best0 - sec0 < MARGIN)
        bj0 = refine_row(x + row0 * DI, kp64, g_sp, b_sp);
    if (best1 - sec1 < MARGIN)
        bj1 = refine_row(x + (row0 + 1) * DI, kp64, g_sp, b_sp);

    // ---- Head: z[c] = zb[c] + sum_s Wb[s]*T[jstar(s),c]; softmax over 7 ----
    // 8 lanes (G&7 = 0..7) cover one batch's 16 rows; reduce via shfl_xor.
    const int s0 = (int)(G & 7) * RPL;
    const float wb0 = Wb[s0], wb1 = Wb[s0 + 1];
    const float* __restrict__ t0 = Tf + bj0 * NC;
    const float* __restrict__ t1 = Tf + bj1 * NC;
    float pz0 = wb0 * t0[0] + wb1 * t1[0];
    float pz1 = wb0 * t0[1] + wb1 * t1[1];
    float pz2 = wb0 * t0[2] + wb1 * t1[2];
    float pz3 = wb0 * t0[3] + wb1 * t1[3];
    float pz4 = wb0 * t0[4] + wb1 * t1[4];
    float pz5 = wb0 * t0[5] + wb1 * t1[5];
    float pz6 = wb0 * t0[6] + wb1 * t1[6];
    #pragma unroll
    for (int m = 1; m < 8; m <<= 1) {
        pz0 += __shfl_xor(pz0, m);
        pz1 += __shfl_xor(pz1, m);
        pz2 += __shfl_xor(pz2, m);
        pz3 += __shfl_xor(pz3, m);
        pz4 += __shfl_xor(pz4, m);
        pz5 += __shfl_xor(pz5, m);
        pz6 += __shfl_xor(pz6, m);
    }
    if ((G & 7) == 0) {
        const long batch = G >> 3;
        const float z0 = pz0 + zbf[0], z1 = pz1 + zbf[1], z2 = pz2 + zbf[2],
                    z3 = pz3 + zbf[3], z4 = pz4 + zbf[4], z5 = pz5 + zbf[5],
                    z6 = pz6 + zbf[6];
        float mx = fmaxf(z0, z1);
        mx = fmaxf(mx, z2); mx = fmaxf(mx, z3); mx = fmaxf(mx, z4);
        mx = fmaxf(mx, z5); mx = fmaxf(mx, z6);
        const float e0 = __expf(z0 - mx), e1 = __expf(z1 - mx),
                    e2 = __expf(z2 - mx), e3 = __expf(z3 - mx),
                    e4 = __expf(z4 - mx), e5 = __expf(z5 - mx),
                    e6 = __expf(z6 - mx);
        const float inv = 1.0f / (e0 + e1 + e2 + e3 + e4 + e5 + e6);
        float* o = out + batch * NC;
        o[0] = e0 * inv; o[1] = e1 * inv; o[2] = e2 * inv; o[3] = e3 * inv;
        o[4] = e4 * inv; o[5] = e5 * inv; o[6] = e6 * inv;
    }
}

extern "C" void kernel_launch(void* const* d_in, const int* in_sizes, int n_in,
                              void* d_out, int out_size, void* d_ws, size_t ws_size,
                              hipStream_t stream) {
    const float* x      = (const float*)d_in[0];
    const float* lookup = (const float*)d_in[1];
    const float* g_st   = (const float*)d_in[2];
    const float* b_st   = (const float*)d_in[3];
    const float* g_sp   = (const float*)d_in[4];
    const float* b_sp   = (const float*)d_in[5];
    const float* g_pp   = (const float*)d_in[6];
    const float* b_pp   = (const float*)d_in[7];
    const float* Wv     = (const float*)d_in[8];
    const float* Wo     = (const float*)d_in[9];
    const float* Wm     = (const float*)d_in[10];
    const float* bm     = (const float*)d_in[11];
    const float* Wb     = (const float*)d_in[12];
    const float* bb     = (const float*)d_in[13];

    double2* kp64 = (double2*)((char*)d_ws + WS_KP64_OFF);
    float*   kf32 = (float*)((char*)d_ws + WS_KF32_OFF);
    float*   Tf   = (float*)((char*)d_ws + WS_TF_OFF);
    float*   zbf  = (float*)((char*)d_ws + WS_ZB_OFF);

    precompute_kernel<<<1, 256, 0, stream>>>(lookup, g_st, b_st, g_pp, b_pp,
                                             Wv, Wo, Wm, bm, Wb, bb,
                                             kp64, kf32, Tf, zbf);
    hopfield_kernel<<<BLOCKS, THREADS, 0, stream>>>(x, g_sp, b_sp, kf32, Tf,
                                                    kp64, zbf, Wb, (float*)d_out);
}

// Round 5
// 412.206 us; speedup vs baseline: 1.4611x; 1.0703x over previous
//
#include <hip/hip_runtime.h>
#include <math.h>

typedef float f2 __attribute__((ext_vector_type(2)));
typedef float f4 __attribute__((ext_vector_type(4)));

// Problem constants (fixed by setup_inputs)
#define BATCH 32768
#define SS 16
#define DI 14
#define BQ 256
#define NC 7
#define RPL 2                                   // rows per lane
#define THREADS 256
#define BLOCKS (BATCH * SS / (THREADS * RPL))   // 1024

// fp32 top-2 gap below which we redo the row's argmax in fp64 (~3e-4 of rows).
#define MARGIN 3.0e-4f

// ws layout
#define WS_KP64_OFF 0                         // double2[256*7]  (28672 B) k fp64, pattern-major
#define WS_KF32_OFF 28672                     // float [256*16]  (16384 B) k fp32, padded to 16
#define WS_TF_OFF   (28672 + 16384)           // float [256*7]   ( 7168 B) per-pattern class table
#define WS_ZB_OFF   (28672 + 16384 + 7168)    // float [7]       head bias: bm*sum(Wb)+bb

__global__ __launch_bounds__(256) void precompute_kernel(
    const float* __restrict__ lookup,
    const float* __restrict__ g_st, const float* __restrict__ b_st,
    const float* __restrict__ g_pp, const float* __restrict__ b_pp,
    const float* __restrict__ Wv,  const float* __restrict__ Wo,
    const float* __restrict__ Wm,  const float* __restrict__ bm,
    const float* __restrict__ Wb,  const float* __restrict__ bb,
    double2* __restrict__ kp64, float* __restrict__ kf32,
    float* __restrict__ Tf, float* __restrict__ zbf)
{
    __shared__ double G1s[256][7];   // (Wo.T @ Wm.T)  : [p][c]
    __shared__ double Gs[14][7];     // Wv.T @ G1      : [d][c]
    const int tid = threadIdx.x;

    {
        const int p = tid;
        for (int c = 0; c < NC; ++c) {
            double acc = 0.0;
            for (int o = 0; o < 28; ++o)
                acc += (double)Wo[o * 256 + p] * (double)Wm[c * 28 + o];
            G1s[p][c] = acc;
        }
    }
    __syncthreads();
    if (tid < DI * NC) {
        const int d = tid / NC, c = tid % NC;
        double acc = 0.0;
        for (int p = 0; p < 256; ++p)
            acc += (double)Wv[p * DI + d] * G1s[p][c];
        Gs[d][c] = acc;
    }
    __syncthreads();

    {
        const int j = tid;
        double xr[DI];
        double sum = 0.0;
        for (int d = 0; d < DI; ++d) { xr[d] = (double)lookup[j * DI + d]; sum += xr[d]; }
        const double mu = sum * (1.0 / (double)DI);
        double vs = 0.0;
        for (int d = 0; d < DI; ++d) { const double t = xr[d] - mu; vs += t * t; }
        const double rs = 1.0 / sqrt(vs * (1.0 / (double)DI) + 1e-5);

        double kj[DI], vl[DI];
        for (int d = 0; d < DI; ++d) {
            const double nrm = (xr[d] - mu) * rs;
            kj[d] = nrm * (double)g_st[d] + (double)b_st[d];
            vl[d] = nrm * (double)g_pp[d] + (double)b_pp[d];
        }
        for (int d2 = 0; d2 < DI / 2; ++d2) {
            double2 kv; kv.x = kj[2 * d2]; kv.y = kj[2 * d2 + 1];
            kp64[j * 7 + d2] = kv;
        }
        for (int d = 0; d < DI; ++d) kf32[j * 16 + d] = (float)kj[d];
        kf32[j * 16 + 14] = 0.0f;
        kf32[j * 16 + 15] = 0.0f;
        for (int c = 0; c < NC; ++c) {
            double acc = 0.0;
            for (int d = 0; d < DI; ++d) acc += vl[d] * Gs[d][c];
            Tf[j * NC + c] = (float)acc;
        }
    }
    if (tid < NC) {
        double wbsum = 0.0;
        for (int s = 0; s < SS; ++s) wbsum += (double)Wb[s];
        zbf[tid] = (float)((double)bm[tid] * wbsum + (double)bb[0]);
    }
}

// Cold path: exact fp64 argmax for one row. __noinline__ keeps its arrays /
// scratch out of the hot kernel's register allocation.
__device__ __noinline__ int refine_row(const float* __restrict__ xrow,
                                       const double2* __restrict__ kp64,
                                       const float* __restrict__ g_sp,
                                       const float* __restrict__ b_sp)
{
    double xv[DI]; double sum = 0.0;
    for (int d = 0; d < DI; ++d) { xv[d] = (double)xrow[d]; sum += xv[d]; }
    const double mu = sum * (1.0 / (double)DI);
    double vs = 0.0;
    for (int d = 0; d < DI; ++d) { const double t = xv[d] - mu; vs += t * t; }
    const double rs = 1.0 / sqrt(vs * (1.0 / (double)DI) + 1e-5);
    double q[DI];
    for (int d = 0; d < DI; ++d)
        q[d] = (xv[d] - mu) * rs * (double)g_sp[d] + (double)b_sp[d];

    double best = -1e300; int bj = 0;
    for (int j = 0; j < BQ; ++j) {
        double a = 0.0;
        for (int d2 = 0; d2 < 7; ++d2) {
            const double2 kv = kp64[j * 7 + d2];
            a += q[2 * d2] * kv.x + q[2 * d2 + 1] * kv.y;
        }
        if (a > best) { best = a; bj = j; }
    }
    return bj;
}

__global__ __launch_bounds__(THREADS, 4) void hopfield_kernel(
    const float* __restrict__ x,
    const float* __restrict__ g_sp, const float* __restrict__ b_sp,
    const float* __restrict__ kf32, const float* __restrict__ Tf,
    const double2* __restrict__ kp64, const float* __restrict__ zbf,
    const float* __restrict__ Wb,
    float* __restrict__ out)
{
    // k table staged in LDS; hot-loop reads are wave-uniform ds_read_b128
    // broadcasts (conflict-free, pipelined) — the k-feed that R4's global
    // uniform loads could not deliver latency-hidden.
    __shared__ f4 ksh[BQ * 4];   // 16384 B

    const int tid = threadIdx.x;
    const long G    = (long)blockIdx.x * THREADS + tid;   // global lane id
    const long row0 = G * RPL;                            // first of 2 owned rows

    {
        const f4* __restrict__ src = (const f4*)kf32;
        #pragma unroll
        for (int i = 0; i < 4; ++i) ksh[i * 256 + tid] = src[i * 256 + tid];
    }

    // ---- Load 2 rows = 28 floats = 7 f4 (112 B per lane, 16B-aligned) ----
    const f4* __restrict__ xp = (const f4*)(x + row0 * DI);
    const f4 xa = xp[0], xb = xp[1], xc = xp[2], xd = xp[3],
             xe = xp[4], xf = xp[5], xg = xp[6];

    // gamma/beta (wave-uniform -> SGPRs)
    const float g0 = g_sp[0], g1 = g_sp[1], g2 = g_sp[2],  g3 = g_sp[3],
                g4 = g_sp[4], g5 = g_sp[5], g6 = g_sp[6],  g7 = g_sp[7],
                g8 = g_sp[8], g9 = g_sp[9], g10 = g_sp[10], g11 = g_sp[11],
                g12 = g_sp[12], g13 = g_sp[13];
    const float h0 = b_sp[0], h1 = b_sp[1], h2 = b_sp[2],  h3 = b_sp[3],
                h4 = b_sp[4], h5 = b_sp[5], h6 = b_sp[6],  h7 = b_sp[7],
                h8 = b_sp[8], h9 = b_sp[9], h10 = b_sp[10], h11 = b_sp[11],
                h12 = b_sp[12], h13 = b_sp[13];

    // ---- fp32 LayerNorm, row 0 (elements xa.x .. xd.y) ----
    f2 qa0, qb0, qc0, qd0, qe0, qf0, qg0;
    {
        const float s = xa.x + xa.y + xa.z + xa.w + xb.x + xb.y + xb.z + xb.w
                      + xc.x + xc.y + xc.z + xc.w + xd.x + xd.y;
        const float mu = s * (1.0f / DI);
        float v = 0.f, t;
        t = xa.x - mu; v = fmaf(t, t, v);  t = xa.y - mu; v = fmaf(t, t, v);
        t = xa.z - mu; v = fmaf(t, t, v);  t = xa.w - mu; v = fmaf(t, t, v);
        t = xb.x - mu; v = fmaf(t, t, v);  t = xb.y - mu; v = fmaf(t, t, v);
        t = xb.z - mu; v = fmaf(t, t, v);  t = xb.w - mu; v = fmaf(t, t, v);
        t = xc.x - mu; v = fmaf(t, t, v);  t = xc.y - mu; v = fmaf(t, t, v);
        t = xc.z - mu; v = fmaf(t, t, v);  t = xc.w - mu; v = fmaf(t, t, v);
        t = xd.x - mu; v = fmaf(t, t, v);  t = xd.y - mu; v = fmaf(t, t, v);
        const float rs = rsqrtf(v * (1.0f / DI) + 1e-5f);
        qa0.x = (xa.x - mu) * rs * g0  + h0;   qa0.y = (xa.y - mu) * rs * g1  + h1;
        qb0.x = (xa.z - mu) * rs * g2  + h2;   qb0.y = (xa.w - mu) * rs * g3  + h3;
        qc0.x = (xb.x - mu) * rs * g4  + h4;   qc0.y = (xb.y - mu) * rs * g5  + h5;
        qd0.x = (xb.z - mu) * rs * g6  + h6;   qd0.y = (xb.w - mu) * rs * g7  + h7;
        qe0.x = (xc.x - mu) * rs * g8  + h8;   qe0.y = (xc.y - mu) * rs * g9  + h9;
        qf0.x = (xc.z - mu) * rs * g10 + h10;  qf0.y = (xc.w - mu) * rs * g11 + h11;
        qg0.x = (xd.x - mu) * rs * g12 + h12;  qg0.y = (xd.y - mu) * rs * g13 + h13;
    }
    // ---- fp32 LayerNorm, row 1 (elements xd.z .. xg.w) ----
    f2 qa1, qb1, qc1, qd1, qe1, qf1, qg1;
    {
        const float s = xd.z + xd.w + xe.x + xe.y + xe.z + xe.w + xf.x + xf.y
                      + xf.z + xf.w + xg.x + xg.y + xg.z + xg.w;
        const float mu = s * (1.0f / DI);
        float v = 0.f, t;
        t = xd.z - mu; v = fmaf(t, t, v);  t = xd.w - mu; v = fmaf(t, t, v);
        t = xe.x - mu; v = fmaf(t, t, v);  t = xe.y - mu; v = fmaf(t, t, v);
        t = xe.z - mu; v = fmaf(t, t, v);  t = xe.w - mu; v = fmaf(t, t, v);
        t = xf.x - mu; v = fmaf(t, t, v);  t = xf.y - mu; v = fmaf(t, t, v);
        t = xf.z - mu; v = fmaf(t, t, v);  t = xf.w - mu; v = fmaf(t, t, v);
        t = xg.x - mu; v = fmaf(t, t, v);  t = xg.y - mu; v = fmaf(t, t, v);
        t = xg.z - mu; v = fmaf(t, t, v);  t = xg.w - mu; v = fmaf(t, t, v);
        const float rs = rsqrtf(v * (1.0f / DI) + 1e-5f);
        qa1.x = (xd.z - mu) * rs * g0  + h0;   qa1.y = (xd.w - mu) * rs * g1  + h1;
        qb1.x = (xe.x - mu) * rs * g2  + h2;   qb1.y = (xe.y - mu) * rs * g3  + h3;
        qc1.x = (xe.z - mu) * rs * g4  + h4;   qc1.y = (xe.w - mu) * rs * g5  + h5;
        qd1.x = (xf.x - mu) * rs * g6  + h6;   qd1.y = (xf.y - mu) * rs * g7  + h7;
        qe1.x = (xf.z - mu) * rs * g8  + h8;   qe1.y = (xf.w - mu) * rs * g9  + h9;
        qf1.x = (xg.x - mu) * rs * g10 + h10;  qf1.y = (xg.y - mu) * rs * g11 + h11;
        qg1.x = (xg.z - mu) * rs * g12 + h12;  qg1.y = (xg.w - mu) * rs * g13 + h13;
    }

    __syncthreads();   // ksh ready

    // ---- Argmax over 256 patterns; k via uniform LDS broadcast reads ----
    float best0 = -3e38f, sec0 = -3e38f, best1 = -3e38f, sec1 = -3e38f;
    int bj0 = 0, bj1 = 0;
    #pragma unroll 4
    for (int j = 0; j < BQ; ++j) {
        const f4 ka = ksh[4 * j + 0];
        const f4 kb = ksh[4 * j + 1];
        const f4 kc = ksh[4 * j + 2];
        const f4 kd = ksh[4 * j + 3];
        f2 k0, k1, k2, k3, k4, k5, k6;
        k0.x = ka.x; k0.y = ka.y;  k1.x = ka.z; k1.y = ka.w;
        k2.x = kb.x; k2.y = kb.y;  k3.x = kb.z; k3.y = kb.w;
        k4.x = kc.x; k4.y = kc.y;  k5.x = kc.z; k5.y = kc.w;
        k6.x = kd.x; k6.y = kd.y;

        f2 acc0 = qa0 * k0;
        acc0 = __builtin_elementwise_fma(qb0, k1, acc0);
        acc0 = __builtin_elementwise_fma(qc0, k2, acc0);
        acc0 = __builtin_elementwise_fma(qd0, k3, acc0);
        acc0 = __builtin_elementwise_fma(qe0, k4, acc0);
        acc0 = __builtin_elementwise_fma(qf0, k5, acc0);
        acc0 = __builtin_elementwise_fma(qg0, k6, acc0);
        const float a0 = acc0.x + acc0.y;

        f2 acc1 = qa1 * k0;
        acc1 = __builtin_elementwise_fma(qb1, k1, acc1);
        acc1 = __builtin_elementwise_fma(qc1, k2, acc1);
        acc1 = __builtin_elementwise_fma(qd1, k3, acc1);
        acc1 = __builtin_elementwise_fma(qe1, k4, acc1);
        acc1 = __builtin_elementwise_fma(qf1, k5, acc1);
        acc1 = __builtin_elementwise_fma(qg1, k6, acc1);
        const float a1 = acc1.x + acc1.y;

        const bool c0 = a0 > best0;
        sec0  = __builtin_amdgcn_fmed3f(a0, best0, sec0);
        best0 = fmaxf(best0, a0);
        bj0   = c0 ? j : bj0;

        const bool c1 = a1 > best1;
        sec1  = __builtin_amdgcn_fmed3f(a1, best1, sec1);
        best1 = fmaxf(best1, a1);
        bj1   = c1 ? j : bj1;
    }

    // ---- Rare fp64 refine when fp32 top-2 gap is inside the error margin ----
    if (best0 - sec0 < MARGIN)
        bj0 = refine_row(x + row0 * DI, kp64, g_sp, b_sp);
    if (best1 - sec1 < MARGIN)
        bj1 = refine_row(x + (row0 + 1) * DI, kp64, g_sp, b_sp);

    // ---- Head: z[c] = zb[c] + sum_s Wb[s]*T[jstar(s),c]; softmax over 7 ----
    // 8 lanes (G&7 = 0..7) cover one batch's 16 rows; reduce via shfl_xor.
    const int s0 = (int)(G & 7) * RPL;
    const float wb0 = Wb[s0], wb1 = Wb[s0 + 1];
    const float* __restrict__ t0 = Tf + bj0 * NC;
    const float* __restrict__ t1 = Tf + bj1 * NC;
    float pz0 = wb0 * t0[0] + wb1 * t1[0];
    float pz1 = wb0 * t0[1] + wb1 * t1[1];
    float pz2 = wb0 * t0[2] + wb1 * t1[2];
    float pz3 = wb0 * t0[3] + wb1 * t1[3];
    float pz4 = wb0 * t0[4] + wb1 * t1[4];
    float pz5 = wb0 * t0[5] + wb1 * t1[5];
    float pz6 = wb0 * t0[6] + wb1 * t1[6];
    #pragma unroll
    for (int m = 1; m < 8; m <<= 1) {
        pz0 += __shfl_xor(pz0, m);
        pz1 += __shfl_xor(pz1, m);
        pz2 += __shfl_xor(pz2, m);
        pz3 += __shfl_xor(pz3, m);
        pz4 += __shfl_xor(pz4, m);
        pz5 += __shfl_xor(pz5, m);
        pz6 += __shfl_xor(pz6, m);
    }
    if ((G & 7) == 0) {
        const long batch = G >> 3;
        const float z0 = pz0 + zbf[0], z1 = pz1 + zbf[1], z2 = pz2 + zbf[2],
                    z3 = pz3 + zbf[3], z4 = pz4 + zbf[4], z5 = pz5 + zbf[5],
                    z6 = pz6 + zbf[6];
        float mx = fmaxf(z0, z1);
        mx = fmaxf(mx, z2); mx = fmaxf(mx, z3); mx = fmaxf(mx, z4);
        mx = fmaxf(mx, z5); mx = fmaxf(mx, z6);
        const float e0 = __expf(z0 - mx), e1 = __expf(z1 - mx),
                    e2 = __expf(z2 - mx), e3 = __expf(z3 - mx),
                    e4 = __expf(z4 - mx), e5 = __expf(z5 - mx),
                    e6 = __expf(z6 - mx);
        const float inv = 1.0f / (e0 + e1 + e2 + e3 + e4 + e5 + e6);
        float* o = out + batch * NC;
        o[0] = e0 * inv; o[1] = e1 * inv; o[2] = e2 * inv; o[3] = e3 * inv;
        o[4] = e4 * inv; o[5] = e5 * inv; o[6] = e6 * inv;
    }
}

extern "C" void kernel_launch(void* const* d_in, const int* in_sizes, int n_in,
                              void* d_out, int out_size, void* d_ws, size_t ws_size,
                              hipStream_t stream) {
    const float* x      = (const float*)d_in[0];
    const float* lookup = (const float*)d_in[1];
    const float* g_st   = (const float*)d_in[2];
    const float* b_st   = (const float*)d_in[3];
    const float* g_sp   = (const float*)d_in[4];
    const float* b_sp   = (const float*)d_in[5];
    const float* g_pp   = (const float*)d_in[6];
    const float* b_pp   = (const float*)d_in[7];
    const float* Wv     = (const float*)d_in[8];
    const float* Wo     = (const float*)d_in[9];
    const float* Wm     = (const float*)d_in[10];
    const float* bm     = (const float*)d_in[11];
    const float* Wb     = (const float*)d_in[12];
    const float* bb     = (const float*)d_in[13];

    double2* kp64 = (double2*)((char*)d_ws + WS_KP64_OFF);
    float*   kf32 = (float*)((char*)d_ws + WS_KF32_OFF);
    float*   Tf   = (float*)((char*)d_ws + WS_TF_OFF);
    float*   zbf  = (float*)((char*)d_ws + WS_ZB_OFF);

    precompute_kernel<<<1, 256, 0, stream>>>(lookup, g_st, b_st, g_pp, b_pp,
                                             Wv, Wo, Wm, bm, Wb, bb,
                                             kp64, kf32, Tf, zbf);
    hopfield_kernel<<<BLOCKS, THREADS, 0, stream>>>(x, g_sp, b_sp, kf32, Tf,
                                                    kp64, zbf, Wb, (float*)d_out);
}

// Round 6
// 411.231 us; speedup vs baseline: 1.4646x; 1.0024x over previous
//
#include <hip/hip_runtime.h>
#include <math.h>

typedef float f2 __attribute__((ext_vector_type(2)));
typedef float f4 __attribute__((ext_vector_type(4)));

// Problem constants (fixed by setup_inputs)
#define BATCH 32768
#define SS 16
#define DI 14
#define BQ 256
#define NC 7
#define RPL 2                                   // rows per lane
#define THREADS 256
#define BLOCKS (BATCH * SS / (THREADS * RPL))   // 1024

// fp32 top-2 gap below which we redo the row's argmax in fp64.
// Worst-case fp32-vs-fp64 ordering error ~1.3e-5 (argmax invariant to the
// per-row LN scale; only elementwise rounding + dot accumulation count).
// 6e-5 = 4-5x cushion; expected refine count ~1e2 rows out of 524288.
#define MARGIN 6.0e-5f

// ws layout
#define WS_KP64_OFF 0                         // double2[256*7]  (28672 B) k fp64, pattern-major
#define WS_KF32_OFF 28672                     // float [256*16]  (16384 B) k fp32, padded to 16
#define WS_TF_OFF   (28672 + 16384)           // float [256*7]   ( 7168 B) per-pattern class table
#define WS_ZB_OFF   (28672 + 16384 + 7168)    // float [7]       head bias: bm*sum(Wb)+bb

__global__ __launch_bounds__(256) void precompute_kernel(
    const float* __restrict__ lookup,
    const float* __restrict__ g_st, const float* __restrict__ b_st,
    const float* __restrict__ g_pp, const float* __restrict__ b_pp,
    const float* __restrict__ Wv,  const float* __restrict__ Wo,
    const float* __restrict__ Wm,  const float* __restrict__ bm,
    const float* __restrict__ Wb,  const float* __restrict__ bb,
    double2* __restrict__ kp64, float* __restrict__ kf32,
    float* __restrict__ Tf, float* __restrict__ zbf)
{
    __shared__ double G1s[256][7];   // (Wo.T @ Wm.T)  : [p][c]
    __shared__ double Gs[14][7];     // Wv.T @ G1      : [d][c]
    const int tid = threadIdx.x;

    {
        const int p = tid;
        for (int c = 0; c < NC; ++c) {
            double acc = 0.0;
            for (int o = 0; o < 28; ++o)
                acc += (double)Wo[o * 256 + p] * (double)Wm[c * 28 + o];
            G1s[p][c] = acc;
        }
    }
    __syncthreads();
    if (tid < DI * NC) {
        const int d = tid / NC, c = tid % NC;
        double acc = 0.0;
        for (int p = 0; p < 256; ++p)
            acc += (double)Wv[p * DI + d] * G1s[p][c];
        Gs[d][c] = acc;
    }
    __syncthreads();

    {
        const int j = tid;
        double xr[DI];
        double sum = 0.0;
        for (int d = 0; d < DI; ++d) { xr[d] = (double)lookup[j * DI + d]; sum += xr[d]; }
        const double mu = sum * (1.0 / (double)DI);
        double vs = 0.0;
        for (int d = 0; d < DI; ++d) { const double t = xr[d] - mu; vs += t * t; }
        const double rs = 1.0 / sqrt(vs * (1.0 / (double)DI) + 1e-5);

        double kj[DI], vl[DI];
        for (int d = 0; d < DI; ++d) {
            const double nrm = (xr[d] - mu) * rs;
            kj[d] = nrm * (double)g_st[d] + (double)b_st[d];
            vl[d] = nrm * (double)g_pp[d] + (double)b_pp[d];
        }
        for (int d2 = 0; d2 < DI / 2; ++d2) {
            double2 kv; kv.x = kj[2 * d2]; kv.y = kj[2 * d2 + 1];
            kp64[j * 7 + d2] = kv;
        }
        for (int d = 0; d < DI; ++d) kf32[j * 16 + d] = (float)kj[d];
        kf32[j * 16 + 14] = 0.0f;
        kf32[j * 16 + 15] = 0.0f;
        for (int c = 0; c < NC; ++c) {
            double acc = 0.0;
            for (int d = 0; d < DI; ++d) acc += vl[d] * Gs[d][c];
            Tf[j * NC + c] = (float)acc;
        }
    }
    if (tid < NC) {
        double wbsum = 0.0;
        for (int s = 0; s < SS; ++s) wbsum += (double)Wb[s];
        zbf[tid] = (float)((double)bm[tid] * wbsum + (double)bb[0]);
    }
}

// Cold path: exact fp64 argmax for one row. __noinline__ keeps its arrays /
// scratch out of the hot kernel's register allocation. Unrolled x4 so the
// 28 global loads per chunk batch in flight (throughput- not latency-bound):
// the R5 version's unroll-1 dependent-load chain made each refining wave a
// 30-100us straggler that dominated the whole dispatch.
__device__ __noinline__ int refine_row(const float* __restrict__ xrow,
                                       const double2* __restrict__ kp64,
                                       const float* __restrict__ g_sp,
                                       const float* __restrict__ b_sp)
{
    double xv[DI]; double sum = 0.0;
    #pragma unroll
    for (int d = 0; d < DI; ++d) { xv[d] = (double)xrow[d]; sum += xv[d]; }
    const double mu = sum * (1.0 / (double)DI);
    double vs = 0.0;
    #pragma unroll
    for (int d = 0; d < DI; ++d) { const double t = xv[d] - mu; vs += t * t; }
    const double rs = 1.0 / sqrt(vs * (1.0 / (double)DI) + 1e-5);
    double q[DI];
    #pragma unroll
    for (int d = 0; d < DI; ++d)
        q[d] = (xv[d] - mu) * rs * (double)g_sp[d] + (double)b_sp[d];

    double best = -1e300; int bj = 0;
    #pragma unroll 4
    for (int j = 0; j < BQ; ++j) {
        double a = 0.0;
        #pragma unroll
        for (int d2 = 0; d2 < 7; ++d2) {
            const double2 kv = kp64[j * 7 + d2];
            a += q[2 * d2] * kv.x + q[2 * d2 + 1] * kv.y;
        }
        if (a > best) { best = a; bj = j; }
    }
    return bj;
}

__global__ __launch_bounds__(THREADS, 4) void hopfield_kernel(
    const float* __restrict__ x,
    const float* __restrict__ g_sp, const float* __restrict__ b_sp,
    const float* __restrict__ kf32, const float* __restrict__ Tf,
    const double2* __restrict__ kp64, const float* __restrict__ zbf,
    const float* __restrict__ Wb,
    float* __restrict__ out)
{
    // k table staged in LDS; hot-loop reads are wave-uniform ds_read_b128
    // broadcasts. Calibrated from R1's counters: uniform-address b128
    // broadcast costs <=2.8 cyc, so the LDS pipe is not a bottleneck here.
    __shared__ f4 ksh[BQ * 4];   // 16384 B

    const int tid = threadIdx.x;
    const long G    = (long)blockIdx.x * THREADS + tid;   // global lane id
    const long row0 = G * RPL;                            // first of 2 owned rows

    {
        const f4* __restrict__ src = (const f4*)kf32;
        #pragma unroll
        for (int i = 0; i < 4; ++i) ksh[i * 256 + tid] = src[i * 256 + tid];
    }

    // ---- Load 2 rows = 28 floats = 7 f4 (112 B per lane, 16B-aligned) ----
    const f4* __restrict__ xp = (const f4*)(x + row0 * DI);
    const f4 xa = xp[0], xb = xp[1], xc = xp[2], xd = xp[3],
             xe = xp[4], xf = xp[5], xg = xp[6];

    // gamma/beta (wave-uniform -> SGPRs)
    const float g0 = g_sp[0], g1 = g_sp[1], g2 = g_sp[2],  g3 = g_sp[3],
                g4 = g_sp[4], g5 = g_sp[5], g6 = g_sp[6],  g7 = g_sp[7],
                g8 = g_sp[8], g9 = g_sp[9], g10 = g_sp[10], g11 = g_sp[11],
                g12 = g_sp[12], g13 = g_sp[13];
    const float h0 = b_sp[0], h1 = b_sp[1], h2 = b_sp[2],  h3 = b_sp[3],
                h4 = b_sp[4], h5 = b_sp[5], h6 = b_sp[6],  h7 = b_sp[7],
                h8 = b_sp[8], h9 = b_sp[9], h10 = b_sp[10], h11 = b_sp[11],
                h12 = b_sp[12], h13 = b_sp[13];

    // ---- fp32 LayerNorm, row 0 (elements xa.x .. xd.y) ----
    f2 qa0, qb0, qc0, qd0, qe0, qf0, qg0;
    {
        const float s = xa.x + xa.y + xa.z + xa.w + xb.x + xb.y + xb.z + xb.w
                      + xc.x + xc.y + xc.z + xc.w + xd.x + xd.y;
        const float mu = s * (1.0f / DI);
        float v = 0.f, t;
        t = xa.x - mu; v = fmaf(t, t, v);  t = xa.y - mu; v = fmaf(t, t, v);
        t = xa.z - mu; v = fmaf(t, t, v);  t = xa.w - mu; v = fmaf(t, t, v);
        t = xb.x - mu; v = fmaf(t, t, v);  t = xb.y - mu; v = fmaf(t, t, v);
        t = xb.z - mu; v = fmaf(t, t, v);  t = xb.w - mu; v = fmaf(t, t, v);
        t = xc.x - mu; v = fmaf(t, t, v);  t = xc.y - mu; v = fmaf(t, t, v);
        t = xc.z - mu; v = fmaf(t, t, v);  t = xc.w - mu; v = fmaf(t, t, v);
        t = xd.x - mu; v = fmaf(t, t, v);  t = xd.y - mu; v = fmaf(t, t, v);
        const float rs = rsqrtf(v * (1.0f / DI) + 1e-5f);
        qa0.x = (xa.x - mu) * rs * g0  + h0;   qa0.y = (xa.y - mu) * rs * g1  + h1;
        qb0.x = (xa.z - mu) * rs * g2  + h2;   qb0.y = (xa.w - mu) * rs * g3  + h3;
        qc0.x = (xb.x - mu) * rs * g4  + h4;   qc0.y = (xb.y - mu) * rs * g5  + h5;
        qd0.x = (xb.z - mu) * rs * g6  + h6;   qd0.y = (xb.w - mu) * rs * g7  + h7;
        qe0.x = (xc.x - mu) * rs * g8  + h8;   qe0.y = (xc.y - mu) * rs * g9  + h9;
        qf0.x = (xc.z - mu) * rs * g10 + h10;  qf0.y = (xc.w - mu) * rs * g11 + h11;
        qg0.x = (xd.x - mu) * rs * g12 + h12;  qg0.y = (xd.y - mu) * rs * g13 + h13;
    }
    // ---- fp32 LayerNorm, row 1 (elements xd.z .. xg.w) ----
    f2 qa1, qb1, qc1, qd1, qe1, qf1, qg1;
    {
        const float s = xd.z + xd.w + xe.x + xe.y + xe.z + xe.w + xf.x + xf.y
                      + xf.z + xf.w + xg.x + xg.y + xg.z + xg.w;
        const float mu = s * (1.0f / DI);
        float v = 0.f, t;
        t = xd.z - mu; v = fmaf(t, t, v);  t = xd.w - mu; v = fmaf(t, t, v);
        t = xe.x - mu; v = fmaf(t, t, v);  t = xe.y - mu; v = fmaf(t, t, v);
        t = xe.z - mu; v = fmaf(t, t, v);  t = xe.w - mu; v = fmaf(t, t, v);
        t = xf.x - mu; v = fmaf(t, t, v);  t = xf.y - mu; v = fmaf(t, t, v);
        t = xf.z - mu; v = fmaf(t, t, v);  t = xf.w - mu; v = fmaf(t, t, v);
        t = xg.x - mu; v = fmaf(t, t, v);  t = xg.y - mu; v = fmaf(t, t, v);
        t = xg.z - mu; v = fmaf(t, t, v);  t = xg.w - mu; v = fmaf(t, t, v);
        const float rs = rsqrtf(v * (1.0f / DI) + 1e-5f);
        qa1.x = (xd.z - mu) * rs * g0  + h0;   qa1.y = (xd.w - mu) * rs * g1  + h1;
        qb1.x = (xe.x - mu) * rs * g2  + h2;   qb1.y = (xe.y - mu) * rs * g3  + h3;
        qc1.x = (xe.z - mu) * rs * g4  + h4;   qc1.y = (xe.w - mu) * rs * g5  + h5;
        qd1.x = (xf.x - mu) * rs * g6  + h6;   qd1.y = (xf.y - mu) * rs * g7  + h7;
        qe1.x = (xf.z - mu) * rs * g8  + h8;   qe1.y = (xf.w - mu) * rs * g9  + h9;
        qf1.x = (xg.x - mu) * rs * g10 + h10;  qf1.y = (xg.y - mu) * rs * g11 + h11;
        qg1.x = (xg.z - mu) * rs * g12 + h12;  qg1.y = (xg.w - mu) * rs * g13 + h13;
    }

    __syncthreads();   // ksh ready

    // ---- Argmax over 256 patterns; k via uniform LDS broadcast reads ----
    float best0 = -3e38f, sec0 = -3e38f, best1 = -3e38f, sec1 = -3e38f;
    int bj0 = 0, bj1 = 0;
    #pragma unroll 4
    for (int j = 0; j < BQ; ++j) {
        const f4 ka = ksh[4 * j + 0];
        const f4 kb = ksh[4 * j + 1];
        const f4 kc = ksh[4 * j + 2];
        const f4 kd = ksh[4 * j + 3];
        f2 k0, k1, k2, k3, k4, k5, k6;
        k0.x = ka.x; k0.y = ka.y;  k1.x = ka.z; k1.y = ka.w;
        k2.x = kb.x; k2.y = kb.y;  k3.x = kb.z; k3.y = kb.w;
        k4.x = kc.x; k4.y = kc.y;  k5.x = kc.z; k5.y = kc.w;
        k6.x = kd.x; k6.y = kd.y;

        f2 acc0 = qa0 * k0;
        acc0 = __builtin_elementwise_fma(qb0, k1, acc0);
        acc0 = __builtin_elementwise_fma(qc0, k2, acc0);
        acc0 = __builtin_elementwise_fma(qd0, k3, acc0);
        acc0 = __builtin_elementwise_fma(qe0, k4, acc0);
        acc0 = __builtin_elementwise_fma(qf0, k5, acc0);
        acc0 = __builtin_elementwise_fma(qg0, k6, acc0);
        const float a0 = acc0.x + acc0.y;

        f2 acc1 = qa1 * k0;
        acc1 = __builtin_elementwise_fma(qb1, k1, acc1);
        acc1 = __builtin_elementwise_fma(qc1, k2, acc1);
        acc1 = __builtin_elementwise_fma(qd1, k3, acc1);
        acc1 = __builtin_elementwise_fma(qe1, k4, acc1);
        acc1 = __builtin_elementwise_fma(qf1, k5, acc1);
        acc1 = __builtin_elementwise_fma(qg1, k6, acc1);
        const float a1 = acc1.x + acc1.y;

        const bool c0 = a0 > best0;
        sec0  = __builtin_amdgcn_fmed3f(a0, best0, sec0);
        best0 = fmaxf(best0, a0);
        bj0   = c0 ? j : bj0;

        const bool c1 = a1 > best1;
        sec1  = __builtin_amdgcn_fmed3f(a1, best1, sec1);
        best1 = fmaxf(best1, a1);
        bj1   = c1 ? j : bj1;
    }

    // ---- Rare fp64 refine when fp32 top-2 gap is inside the error margin ----
    if (best0 - sec0 < MARGIN)
        bj0 = refine_row(x + row0 * DI, kp64, g_sp, b_sp);
    if (best1 - sec1 < MARGIN)
        bj1 = refine_row(x + (row0 + 1) * DI, kp64, g_sp, b_sp);

    // ---- Head: z[c] = zb[c] + sum_s Wb[s]*T[jstar(s),c]; softmax over 7 ----
    // 8 lanes (G&7 = 0..7) cover one batch's 16 rows; reduce via shfl_xor.
    const int s0 = (int)(G & 7) * RPL;
    const float wb0 = Wb[s0], wb1 = Wb[s0 + 1];
    const float* __restrict__ t0 = Tf + bj0 * NC;
    const float* __restrict__ t1 = Tf + bj1 * NC;
    float pz0 = wb0 * t0[0] + wb1 * t1[0];
    float pz1 = wb0 * t0[1] + wb1 * t1[1];
    float pz2 = wb0 * t0[2] + wb1 * t1[2];
    float pz3 = wb0 * t0[3] + wb1 * t1[3];
    float pz4 = wb0 * t0[4] + wb1 * t1[4];
    float pz5 = wb0 * t0[5] + wb1 * t1[5];
    float pz6 = wb0 * t0[6] + wb1 * t1[6];
    #pragma unroll
    for (int m = 1; m < 8; m <<= 1) {
        pz0 += __shfl_xor(pz0, m);
        pz1 += __shfl_xor(pz1, m);
        pz2 += __shfl_xor(pz2, m);
        pz3 += __shfl_xor(pz3, m);
        pz4 += __shfl_xor(pz4, m);
        pz5 += __shfl_xor(pz5, m);
        pz6 += __shfl_xor(pz6, m);
    }
    if ((G & 7) == 0) {
        const long batch = G >> 3;
        const float z0 = pz0 + zbf[0], z1 = pz1 + zbf[1], z2 = pz2 + zbf[2],
                    z3 = pz3 + zbf[3], z4 = pz4 + zbf[4], z5 = pz5 + zbf[5],
                    z6 = pz6 + zbf[6];
        float mx = fmaxf(z0, z1);
        mx = fmaxf(mx, z2); mx = fmaxf(mx, z3); mx = fmaxf(mx, z4);
        mx = fmaxf(mx, z5); mx = fmaxf(mx, z6);
        const float e0 = __expf(z0 - mx), e1 = __expf(z1 - mx),
                    e2 = __expf(z2 - mx), e3 = __expf(z3 - mx),
                    e4 = __expf(z4 - mx), e5 = __expf(z5 - mx),
                    e6 = __expf(z6 - mx);
        const float inv = 1.0f / (e0 + e1 + e2 + e3 + e4 + e5 + e6);
        float* o = out + batch * NC;
        o[0] = e0 * inv; o[1] = e1 * inv; o[2] = e2 * inv; o[3] = e3 * inv;
        o[4] = e4 * inv; o[5] = e5 * inv; o[6] = e6 * inv;
    }
}

extern "C" void kernel_launch(void* const* d_in, const int* in_sizes, int n_in,
                              void* d_out, int out_size, void* d_ws, size_t ws_size,
                              hipStream_t stream) {
    const float* x      = (const float*)d_in[0];
    const float* lookup = (const float*)d_in[1];
    const float* g_st   = (const float*)d_in[2];
    const float* b_st   = (const float*)d_in[3];
    const float* g_sp   = (const float*)d_in[4];
    const float* b_sp   = (const float*)d_in[5];
    const float* g_pp   = (const float*)d_in[6];
    const float* b_pp   = (const float*)d_in[7];
    const float* Wv     = (const float*)d_in[8];
    const float* Wo     = (const float*)d_in[9];
    const float* Wm     = (const float*)d_in[10];
    const float* bm     = (const float*)d_in[11];
    const float* Wb     = (const float*)d_in[12];
    const float* bb     = (const float*)d_in[13];

    double2* kp64 = (double2*)((char*)d_ws + WS_KP64_OFF);
    float*   kf32 = (float*)((char*)d_ws + WS_KF32_OFF);
    float*   Tf   = (float*)((char*)d_ws + WS_TF_OFF);
    float*   zbf  = (float*)((char*)d_ws + WS_ZB_OFF);

    precompute_kernel<<<1, 256, 0, stream>>>(lookup, g_st, b_st, g_pp, b_pp,
                                             Wv, Wo, Wm, bm, Wb, bb,
                                             kp64, kf32, Tf, zbf);
    hopfield_kernel<<<BLOCKS, THREADS, 0, stream>>>(x, g_sp, b_sp, kf32, Tf,
                                                    kp64, zbf, Wb, (float*)d_out);
}